// Round 1
// baseline (1506.119 us; speedup 1.0000x reference)
//
#include <hip/hip_runtime.h>
#include <hip/hip_bf16.h>

// CARAFE: X(16,256,80,80) -> out(16,256,160,160), fp32.
// K1: 1x1 conv (256->64) + BN + SiLU          -> Y   (ws)
// K2: 3x3 conv (64->100) + BN + PixelShuffle(2) + softmax(25) -> Wsm (ws)
// K3: out[b,c,2h+si,2w+sj] = sum_t Wsm[b,t,2h+si,2w+sj] * X[b,c,h+t/5-2,w+t%5-2]

#define NB   16
#define CIN  256
#define HH   80
#define WW   80
#define HWP  6400      // 80*80
#define CMID 64
#define OH   160
#define OW   160
#define OHW  25600     // 160*160

// ---------------- K1: 1x1 conv + BN + SiLU ----------------
// grid 400 x 256 threads; thread = one pixel, 64 output channels in regs.
// Weights staged transposed [c][64] in two 32KB halves (LDS broadcast b128).
__global__ __launch_bounds__(256) void k1_conv1x1(
    const float* __restrict__ X, const float* __restrict__ Wc,
    const float* __restrict__ g1, const float* __restrict__ b1,
    const float* __restrict__ m1, const float* __restrict__ v1,
    float* __restrict__ Y) {
  __shared__ float wlds[128 * 64];  // 32 KB
  const int tid = threadIdx.x;
  const int p = blockIdx.x * 256 + tid;   // 0..102399, b uniform per block
  const int b = p / HWP;
  const int hw = p - b * HWP;
  const float* Xb = X + (size_t)b * CIN * HWP + hw;

  float acc[64];
#pragma unroll
  for (int i = 0; i < 64; ++i) acc[i] = 0.f;

  for (int half = 0; half < 2; ++half) {
    __syncthreads();
    for (int i = tid; i < 128 * 64; i += 256) {
      int cl = i >> 6, oc = i & 63;
      wlds[i] = Wc[(size_t)oc * CIN + half * 128 + cl];
    }
    __syncthreads();
#pragma unroll 4
    for (int cl = 0; cl < 128; ++cl) {
      float xv = Xb[(size_t)(half * 128 + cl) * HWP];
      const float4* wr = (const float4*)&wlds[cl * 64];
#pragma unroll
      for (int j = 0; j < 16; ++j) {
        float4 wv = wr[j];
        acc[j * 4 + 0] += wv.x * xv;
        acc[j * 4 + 1] += wv.y * xv;
        acc[j * 4 + 2] += wv.z * xv;
        acc[j * 4 + 3] += wv.w * xv;
      }
    }
  }

  float* Yb = Y + (size_t)b * CMID * HWP + hw;
#pragma unroll
  for (int oc = 0; oc < 64; ++oc) {
    float inv = g1[oc] * rsqrtf(v1[oc] + 1e-5f);   // uniform -> s_loads
    float v = acc[oc] * inv + (b1[oc] - m1[oc] * inv);
    Yb[(size_t)oc * HWP] = v / (1.f + __expf(-v)); // SiLU
  }
}

// ---------------- K2: 3x3 conv + BN + softmax (per pixelshuffle offset) ----
// grid (10, 16, 4): z = off = si*2+sj; block 320 threads, 2 pixels/thread.
// LDS: scaled weights [576][28] (63 KB), channels ch = q*4+off, q=0..24.
__global__ __launch_bounds__(320) void k2_conv3x3_softmax(
    const float* __restrict__ Y, const float* __restrict__ We,
    const float* __restrict__ g2, const float* __restrict__ b2,
    const float* __restrict__ m2, const float* __restrict__ v2,
    float* __restrict__ Wsm) {
  __shared__ float wlds[576 * 28];  // 64512 B
  const int tid = threadIdx.x;
  const int b = blockIdx.y;
  const int off = blockIdx.z;
  const int si = off >> 1, sj = off & 1;

  for (int i = tid; i < 576 * 25; i += 320) {
    int k576 = i / 25, q = i - k576 * 25;
    int ch = q * 4 + off;
    float inv = g2[ch] * rsqrtf(v2[ch] + 1e-5f);
    wlds[k576 * 28 + q] = We[(size_t)ch * 576 + k576] * inv;
  }
  __syncthreads();

  const int p0 = blockIdx.x * 640 + tid;  // [0,6400) exact coverage
  const int p1 = p0 + 320;
  const int h0 = p0 / 80, w0 = p0 - h0 * 80;
  const int h1 = p1 / 80, w1 = p1 - h1 * 80;
  const float* Yb = Y + (size_t)b * CMID * HWP;

  float acc0[25], acc1[25];
#pragma unroll
  for (int q = 0; q < 25; ++q) { acc0[q] = 0.f; acc1[q] = 0.f; }

  // hoisted boundary predicates
  bool rv0[3], cv0[3], rv1[3], cv1[3];
  int ro0[3], co0[3], ro1[3], co1[3];
#pragma unroll
  for (int d = 0; d < 3; ++d) {
    int r0 = h0 + d - 1, c0 = w0 + d - 1, r1 = h1 + d - 1, c1 = w1 + d - 1;
    rv0[d] = (r0 >= 0 && r0 < 80); ro0[d] = r0 * 80;
    cv0[d] = (c0 >= 0 && c0 < 80); co0[d] = c0;
    rv1[d] = (r1 >= 0 && r1 < 80); ro1[d] = r1 * 80;
    cv1[d] = (c1 >= 0 && c1 < 80); co1[d] = c1;
  }

  for (int c = 0; c < 64; ++c) {
    float ya[9], yb[9];
    const float* Yc = Yb + (size_t)c * HWP;
#pragma unroll
    for (int dh = 0; dh < 3; ++dh)
#pragma unroll
      for (int dw = 0; dw < 3; ++dw) {
        ya[dh * 3 + dw] = (rv0[dh] && cv0[dw]) ? Yc[ro0[dh] + co0[dw]] : 0.f;
        yb[dh * 3 + dw] = (rv1[dh] && cv1[dw]) ? Yc[ro1[dh] + co1[dw]] : 0.f;
      }
#pragma unroll
    for (int k = 0; k < 9; ++k) {
      const float4* wr = (const float4*)&wlds[(c * 9 + k) * 28];
      float xa = ya[k], xb = yb[k];
#pragma unroll
      for (int j = 0; j < 6; ++j) {
        float4 wv = wr[j];
        acc0[j * 4 + 0] += wv.x * xa; acc1[j * 4 + 0] += wv.x * xb;
        acc0[j * 4 + 1] += wv.y * xa; acc1[j * 4 + 1] += wv.y * xb;
        acc0[j * 4 + 2] += wv.z * xa; acc1[j * 4 + 2] += wv.z * xb;
        acc0[j * 4 + 3] += wv.w * xa; acc1[j * 4 + 3] += wv.w * xb;
      }
      float wl = wlds[(c * 9 + k) * 28 + 24];
      acc0[24] += wl * xa; acc1[24] += wl * xb;
    }
  }

  // bias + softmax + strided (pixelshuffle) write, both pixels
#pragma unroll 1
  for (int px = 0; px < 2; ++px) {
    float* a = px ? acc1 : acc0;
    int h = px ? h1 : h0, w = px ? w1 : w0;
    float mx = -3.4e38f;
#pragma unroll
    for (int q = 0; q < 25; ++q) {
      int ch = q * 4 + off;
      float inv = g2[ch] * rsqrtf(v2[ch] + 1e-5f);  // uniform -> s_loads
      a[q] += b2[ch] - m2[ch] * inv;
      mx = fmaxf(mx, a[q]);
    }
    float s = 0.f;
#pragma unroll
    for (int q = 0; q < 25; ++q) { a[q] = __expf(a[q] - mx); s += a[q]; }
    float rs = 1.f / s;
    size_t base = (size_t)b * 25 * OHW + (size_t)(2 * h + si) * OW + (2 * w + sj);
#pragma unroll
    for (int q = 0; q < 25; ++q) Wsm[base + (size_t)q * OHW] = a[q] * rs;
  }
}

// ---------------- K3: CARAFE gather ----------------
// grid (5 wtiles, 80 h, 16 b); block 256 = 16 wl x 16 ci.
// Per thread: 100 weights in VGPRs (constant over c), 25 shared X taps
// feed 4 outputs (si,sj), stored as two coalesced float2.
__global__ __launch_bounds__(256) void k3_carafe(
    const float* __restrict__ X, const float* __restrict__ Wsm,
    float* __restrict__ Out) {
  __shared__ float wlds[1600];      // [ss*25+t][wl]
  __shared__ float xlds[32 * 105];  // [cl][di*21 + j], j in [0,20) + pad

  const int tid = threadIdx.x;
  const int wt = blockIdx.x;  // w-tile (16 wide)
  const int h = blockIdx.y;
  const int b = blockIdx.z;
  const int wl = tid & 15, ci = tid >> 4;

  for (int i = tid; i < 1600; i += 256) {
    int wli = i & 15;
    int r = i >> 4;            // ss*25+t
    int t = r % 25, ss = r / 25;
    int sy = ss >> 1, sx = ss & 1;
    wlds[i] = Wsm[(size_t)(b * 25 + t) * OHW + (size_t)(2 * h + sy) * OW +
                  wt * 32 + 2 * wli + sx];
  }
  __syncthreads();

  float wr[100];
#pragma unroll
  for (int r = 0; r < 100; ++r) wr[r] = wlds[r * 16 + wl];

  const float* Xb = X + (size_t)b * CIN * HWP;

  for (int cc = 0; cc < 8; ++cc) {
    __syncthreads();
    for (int i = tid; i < 3200; i += 256) {
      int cl = i / 100;
      int rem = i - cl * 100;
      int di = rem / 20, j = rem - di * 20;
      int r = h + di - 2;
      int col = wt * 16 + j - 2;
      float v = 0.f;
      if (r >= 0 && r < 80 && col >= 0 && col < 80)
        v = Xb[(size_t)(cc * 32 + cl) * HWP + r * 80 + col];
      xlds[cl * 105 + di * 21 + j] = v;
    }
    __syncthreads();
#pragma unroll
    for (int half = 0; half < 2; ++half) {
      int cl = ci + half * 16;
      int c = cc * 32 + cl;
      float xp[25];
#pragma unroll
      for (int t = 0; t < 25; ++t)
        xp[t] = xlds[cl * 105 + (t / 5) * 21 + wl + (t % 5)];
      float a00 = 0.f, a01 = 0.f, a10 = 0.f, a11 = 0.f;
#pragma unroll
      for (int t = 0; t < 25; ++t) {
        a00 += wr[t] * xp[t];
        a01 += wr[25 + t] * xp[t];
        a10 += wr[50 + t] * xp[t];
        a11 += wr[75 + t] * xp[t];
      }
      size_t ob = (size_t)(b * 256 + c) * OHW + (size_t)(2 * h) * OW +
                  wt * 32 + 2 * wl;
      *(float2*)&Out[ob] = make_float2(a00, a01);
      *(float2*)&Out[ob + OW] = make_float2(a10, a11);
    }
  }
}

extern "C" void kernel_launch(void* const* d_in, const int* in_sizes, int n_in,
                              void* d_out, int out_size, void* d_ws, size_t ws_size,
                              hipStream_t stream) {
  const float* X  = (const float*)d_in[0];
  const float* Wc = (const float*)d_in[1];
  const float* g1 = (const float*)d_in[2];
  const float* b1 = (const float*)d_in[3];
  const float* m1 = (const float*)d_in[4];
  const float* v1 = (const float*)d_in[5];
  const float* We = (const float*)d_in[6];
  const float* g2 = (const float*)d_in[7];
  const float* b2 = (const float*)d_in[8];
  const float* m2 = (const float*)d_in[9];
  const float* v2 = (const float*)d_in[10];
  float* Out = (float*)d_out;

  float* Y   = (float*)d_ws;                                   // 26,214,400 B
  float* Wsm = (float*)((char*)d_ws + (size_t)26214400);       // 40,960,000 B

  k1_conv1x1<<<400, 256, 0, stream>>>(X, Wc, g1, b1, m1, v1, Y);
  k2_conv3x3_softmax<<<dim3(10, 16, 4), 320, 0, stream>>>(Y, We, g2, b2, m2, v2, Wsm);
  k3_carafe<<<dim3(5, 80, 16), 256, 0, stream>>>(X, Wsm, Out);
}

// Round 4
// 1314.470 us; speedup vs baseline: 1.1458x; 1.1458x over previous
//
#include <hip/hip_runtime.h>
#include <hip/hip_bf16.h>

// CARAFE: X(16,256,80,80) -> out(16,256,160,160), fp32.
// K1: 1x1 conv (256->64) + BN + SiLU          -> Y   (ws)
// K2: 3x3 conv (64->100) + BN + softmax(25)   -> Wsm (ws, dense [b][t][ss][80][80])
// K3: out[b,c,2h+si,2w+sj] = sum_t Wsm[b,t,ss,h,w] * X[b,c,h+t/5-2,w+t%5-2]

#define HWP  6400      // 80*80
#define OHW  25600     // 160*160

// ---------------- K1: 1x1 conv + BN + SiLU ----------------
__global__ __launch_bounds__(256) void k1_conv1x1(
    const float* __restrict__ X, const float* __restrict__ Wc,
    const float* __restrict__ g1, const float* __restrict__ b1,
    const float* __restrict__ m1, const float* __restrict__ v1,
    float* __restrict__ Y) {
  __shared__ float wlds[128 * 64];  // 32 KB
  const int tid = threadIdx.x;
  const int p = blockIdx.x * 256 + tid;   // b uniform per block
  const int b = p / HWP;
  const int hw = p - b * HWP;
  const float* Xb = X + (size_t)b * 256 * HWP + hw;

  float acc[64];
#pragma unroll
  for (int i = 0; i < 64; ++i) acc[i] = 0.f;

  for (int half = 0; half < 2; ++half) {
    __syncthreads();
    for (int i = tid; i < 128 * 64; i += 256) {
      int cl = i >> 6, oc = i & 63;
      wlds[i] = Wc[(size_t)oc * 256 + half * 128 + cl];
    }
    __syncthreads();
#pragma unroll 4
    for (int cl = 0; cl < 128; ++cl) {
      float xv = Xb[(size_t)(half * 128 + cl) * HWP];
      const float4* wr = (const float4*)&wlds[cl * 64];
#pragma unroll
      for (int j = 0; j < 16; ++j) {
        float4 wv = wr[j];
        acc[j * 4 + 0] += wv.x * xv;
        acc[j * 4 + 1] += wv.y * xv;
        acc[j * 4 + 2] += wv.z * xv;
        acc[j * 4 + 3] += wv.w * xv;
      }
    }
  }

  float* Yb = Y + (size_t)b * 64 * HWP + hw;
#pragma unroll
  for (int oc = 0; oc < 64; ++oc) {
    float inv = g1[oc] * rsqrtf(v1[oc] + 1e-5f);   // uniform -> s_loads
    float v = acc[oc] * inv + (b1[oc] - m1[oc] * inv);
    Yb[(size_t)oc * HWP] = v / (1.f + __expf(-v)); // SiLU
  }
}

// ---------------- K2: 3x3 conv + BN + softmax (per pixelshuffle offset) ----
// grid (10, 16, 4): z = off = si*2+sj; 320 threads, 2 px/thread (8 h-rows/blk).
// Y staged in LDS per 8-channel chunk; scaled weights chunked [c'*9+k][28].
__global__ __launch_bounds__(320) void k2_conv3x3_softmax(
    const float* __restrict__ Y, const float* __restrict__ We,
    const float* __restrict__ g2, const float* __restrict__ b2,
    const float* __restrict__ m2, const float* __restrict__ v2,
    float* __restrict__ Wsm) {
  __shared__ float ylds[6400];     // 8c x 10rows x 80 (25.6 KB)
  __shared__ float wlds[72 * 28];  // 8c x 9k x 25q (+pad)  (8.1 KB)
  const int tid = threadIdx.x;
  const int bx = blockIdx.x;
  const int b = blockIdx.y;
  const int off = blockIdx.z;
  const int h0 = bx * 8;

  const int p0 = bx * 640 + tid;
  const int p1 = p0 + 320;
  const int h0p = p0 / 80, w0 = p0 - h0p * 80;
  const int h1p = p1 / 80, w1 = p1 - h1p * 80;
  const int lr0 = h0p - h0, lr1 = h1p - h0;   // 0..3 / 4..7

  // cc-invariant fill decode: 20 Y elements per thread
  int gy[20];
  unsigned ymask = 0;
#pragma unroll
  for (int k = 0; k < 20; ++k) {
    int i = k * 320 + tid;                 // 0..6399
    int cl = (unsigned)i / 800u;           // 0..7
    int rem = i - cl * 800;
    int r = (unsigned)rem / 80u;           // 0..9, global row h0-1+r
    int col = rem - r * 80;
    int grow = h0 - 1 + r;
    gy[k] = ((b * 64 + cl) * 80 + grow) * 80 + col;
    if (grow >= 0 && grow < 80) ymask |= (1u << k);
  }

  float acc0[25], acc1[25];
#pragma unroll
  for (int q = 0; q < 25; ++q) { acc0[q] = 0.f; acc1[q] = 0.f; }

  // col-halo predicates
  bool cv0[3], cv1[3];
  int co0[3], co1[3];
#pragma unroll
  for (int d = 0; d < 3; ++d) {
    int c0 = w0 - 1 + d, c1 = w1 - 1 + d;
    cv0[d] = (c0 >= 0 && c0 < 80); co0[d] = c0;
    cv1[d] = (c1 >= 0 && c1 < 80); co1[d] = c1;
  }

  for (int cc = 0; cc < 8; ++cc) {
    __syncthreads();
#pragma unroll
    for (int k = 0; k < 20; ++k) {
      float v = 0.f;
      if (ymask & (1u << k)) v = Y[gy[k] + cc * 8 * HWP];
      ylds[k * 320 + tid] = v;
    }
    for (int i = tid; i < 1800; i += 320) {
      int rw = (unsigned)i / 25u, q = i - rw * 25;  // rw = c'*9+k
      int ch = q * 4 + off;
      float inv = g2[ch] * rsqrtf(v2[ch] + 1e-5f);
      wlds[rw * 28 + q] = We[(size_t)ch * 576 + cc * 72 + rw] * inv;
    }
    __syncthreads();

    for (int c8 = 0; c8 < 8; ++c8) {
      float ya[9], yb[9];
      const float* yc = &ylds[c8 * 800];
#pragma unroll
      for (int dh = 0; dh < 3; ++dh)
#pragma unroll
        for (int dw = 0; dw < 3; ++dw) {
          ya[dh * 3 + dw] = cv0[dw] ? yc[(lr0 + dh) * 80 + co0[dw]] : 0.f;
          yb[dh * 3 + dw] = cv1[dw] ? yc[(lr1 + dh) * 80 + co1[dw]] : 0.f;
        }
#pragma unroll
      for (int k = 0; k < 9; ++k) {
        const float4* wrp = (const float4*)&wlds[(c8 * 9 + k) * 28];
        float xa = ya[k], xb = yb[k];
#pragma unroll
        for (int j = 0; j < 6; ++j) {
          float4 wv = wrp[j];
          acc0[j * 4 + 0] += wv.x * xa; acc1[j * 4 + 0] += wv.x * xb;
          acc0[j * 4 + 1] += wv.y * xa; acc1[j * 4 + 1] += wv.y * xb;
          acc0[j * 4 + 2] += wv.z * xa; acc1[j * 4 + 2] += wv.z * xb;
          acc0[j * 4 + 3] += wv.w * xa; acc1[j * 4 + 3] += wv.w * xb;
        }
        float wl = wlds[(c8 * 9 + k) * 28 + 24];
        acc0[24] += wl * xa; acc1[24] += wl * xb;
      }
    }
  }

  // bias + softmax + dense store (no runtime array select -> regs stay regs)
  auto epi = [&](float (&a)[25], int h, int w) {
    float mx = -3.4e38f;
#pragma unroll
    for (int q = 0; q < 25; ++q) {
      int ch = q * 4 + off;
      float inv = g2[ch] * rsqrtf(v2[ch] + 1e-5f);  // uniform -> s_loads
      a[q] += b2[ch] - m2[ch] * inv;
      mx = fmaxf(mx, a[q]);
    }
    float s = 0.f;
#pragma unroll
    for (int q = 0; q < 25; ++q) { a[q] = __expf(a[q] - mx); s += a[q]; }
    float rs = 1.f / s;
    size_t base = ((size_t)(b * 25) * 4 + off) * HWP + h * 80 + w;
#pragma unroll
    for (int q = 0; q < 25; ++q) Wsm[base + (size_t)q * 4 * HWP] = a[q] * rs;
  };
  epi(acc0, h0p, w0);
  epi(acc1, h1p, w1);
}

// ---------------- K3: CARAFE gather ----------------
// grid 6400 (XCD-swizzled); block 256 = 16 wl x 16 ci.
// 100 weights/thread in VGPRs (LDS region aliased so compiler can't re-fold),
// X chunk [16c][5r][24j] double-buffered, taps via immediate-offset ds_reads.
#define XDIM 1920   // 16*5*24

__global__ __launch_bounds__(256, 3) void k3_carafe(
    const float* __restrict__ X, const float* __restrict__ Wsm,
    float* __restrict__ Out) {
  __shared__ float lds[3840];  // [0,1600): weight stage, then x dbuf 2x1920
  const int tid = threadIdx.x;
  const int bid = blockIdx.x;
  const int swz = (bid & 7) * 800 + (bid >> 3);   // bijective, 6400%8==0
  const int wt = swz % 5;
  const int h = (swz / 5) % 80;
  const int b = swz / 400;
  const int wl = tid & 15, ci = tid >> 4;

  // stage weights [r=ss*25+t][16] from dense Wsm
  for (int i = tid; i < 1600; i += 256) {
    int wli = i & 15, r = i >> 4;
    int t = r % 25, ss = r / 25;
    lds[i] = Wsm[(size_t)((b * 25 + t) * 4 + ss) * HWP + h * 80 + wt * 16 + wli];
  }
  __syncthreads();
  float wr[100];
#pragma unroll
  for (int r = 0; r < 100; ++r) wr[r] = lds[r * 16 + wl];
  __syncthreads();   // lds reused below => wr must live in VGPRs

  // cc-invariant fill decode: 8 X elements per thread
  int gofs[8];
  unsigned vmask = 0;
#pragma unroll
  for (int k = 0; k < 8; ++k) {
    int i = k * 256 + tid;
    int cl = (unsigned)i / 120u;
    int rem = i - cl * 120;
    int di = (unsigned)rem / 24u;
    int j = rem - di * 24;
    int row = h + di - 2;
    int col = wt * 16 + j - 2;
    bool ok = (i < XDIM) && (j < 20) && row >= 0 && row < 80 && col >= 0 && col < 80;
    gofs[k] = ((b * 256 + cl) * 80 + row) * 80 + col;
    if (ok) vmask |= (1u << k);
  }

  // prologue: chunk 0 -> buf0
#pragma unroll
  for (int k = 0; k < 8; ++k) {
    int i = k * 256 + tid;
    float v = 0.f;
    if (vmask & (1u << k)) v = X[gofs[k]];
    if (i < XDIM) lds[i] = v;
  }
  __syncthreads();

  const int xbase = ci * 120 + wl;
  size_t obase = ((size_t)(b * 256 + ci) * 160 + 2 * h) * 160 + wt * 32 + 2 * wl;

#pragma unroll 2
  for (int cc = 0; cc < 16; ++cc) {
    const int cur = (cc & 1) * XDIM;
    const int nxt = XDIM - cur;

    float pv[8];
    if (cc < 15) {   // prefetch next chunk (global -> regs), latency under FMA
#pragma unroll
      for (int k = 0; k < 8; ++k) {
        pv[k] = 0.f;
        if (vmask & (1u << k)) pv[k] = X[gofs[k] + (cc + 1) * 16 * HWP];
      }
    }

    const float* xb = &lds[cur + xbase];
    float a00 = 0.f, a01 = 0.f, a10 = 0.f, a11 = 0.f;
#pragma unroll
    for (int t = 0; t < 25; ++t) {
      float xv = xb[(t / 5) * 24 + (t % 5)];   // immediate-offset ds_read
      a00 += wr[t] * xv;
      a01 += wr[25 + t] * xv;
      a10 += wr[50 + t] * xv;
      a11 += wr[75 + t] * xv;
    }

    if (cc < 15) {
#pragma unroll
      for (int k = 0; k < 8; ++k) {
        int i = k * 256 + tid;
        if (i < XDIM) lds[nxt + i] = pv[k];
      }
    }

    float* op = Out + obase + (size_t)cc * 16 * OHW;
    *(float2*)op = make_float2(a00, a01);
    *(float2*)(op + 160) = make_float2(a10, a11);
    __syncthreads();
  }
}

extern "C" void kernel_launch(void* const* d_in, const int* in_sizes, int n_in,
                              void* d_out, int out_size, void* d_ws, size_t ws_size,
                              hipStream_t stream) {
  const float* X  = (const float*)d_in[0];
  const float* Wc = (const float*)d_in[1];
  const float* g1 = (const float*)d_in[2];
  const float* b1 = (const float*)d_in[3];
  const float* m1 = (const float*)d_in[4];
  const float* v1 = (const float*)d_in[5];
  const float* We = (const float*)d_in[6];
  const float* g2 = (const float*)d_in[7];
  const float* b2 = (const float*)d_in[8];
  const float* m2 = (const float*)d_in[9];
  const float* v2 = (const float*)d_in[10];
  float* Out = (float*)d_out;

  float* Y   = (float*)d_ws;                              // 26,214,400 B
  float* Wsm = (float*)((char*)d_ws + (size_t)26214400);  // 40,960,000 B dense

  k1_conv1x1<<<400, 256, 0, stream>>>(X, Wc, g1, b1, m1, v1, Y);
  k2_conv3x3_softmax<<<dim3(10, 16, 4), 320, 0, stream>>>(Y, We, g2, b2, m2, v2, Wsm);
  k3_carafe<<<dim3(6400), 256, 0, stream>>>(X, Wsm, Out);
}